// Round 2
// baseline (250.740 us; speedup 1.0000x reference)
//
#include <hip/hip_runtime.h>

#define SEQ 32768
#define QSCALE 0.08838834764831845f

typedef __attribute__((ext_vector_type(8))) short short8;
typedef __attribute__((ext_vector_type(4))) short s16x4;
typedef __attribute__((ext_vector_type(8))) __bf16 bf16x8;
typedef __attribute__((ext_vector_type(16))) float f32x16;
typedef __attribute__((ext_vector_type(4))) float f32x4;

// short-index swizzles (byte-bit 4..6 XOR): conflict-free MFMA-frag reads
#define SWZ(r, c) ((((r) << 7) + (c)) ^ (((r) & 7) << 3))   // [R][128] tiles
#define TSWZ(d, k) ((((d) << 5) + (k)) ^ (((d) & 7) << 3))  // [128][32] tiles

__device__ __forceinline__ short bf16b(float f) {
  unsigned u = __builtin_bit_cast(unsigned, f);
  u += 0x7fffu + ((u >> 16) & 1u);   // RNE
  return (short)(u >> 16);
}

__device__ __forceinline__ f32x16 mfma_pp(const short* pa, const short* pb, f32x16 c) {
  return __builtin_amdgcn_mfma_f32_32x32x16_bf16(*(const bf16x8*)pa, *(const bf16x8*)pb, c, 0, 0, 0);
}
__device__ __forceinline__ f32x16 mfma_pr(const short* pa, short8 b, f32x16 c) {
  return __builtin_amdgcn_mfma_f32_32x32x16_bf16(*(const bf16x8*)pa, __builtin_bit_cast(bf16x8, b), c, 0, 0, 0);
}

// ---------------------------------------------------------------------------
// Pass 1: q,k proj + softmax(in-reg) + ctx partial.  grid 8*strips, 512 thr.
// ---------------------------------------------------------------------------
__global__ __launch_bounds__(512, 4)
void la_pass1(const float* __restrict__ x, const float* __restrict__ Wqkv,
              float* __restrict__ partials, int strips, int nch) {
  __shared__ __align__(16) short xs[2][32 * 128];   // 16 KB dbuf
  __shared__ __align__(16) short qt[128 * 32];      // 8 KB  [channel][kk]
  __shared__ __align__(16) short kt[128 * 32];      // 8 KB
  __shared__ __align__(16) float sumbuf[2][32][4];  // 1 KB

  const int tid = threadIdx.x;
  const int lane = tid & 63;
  const int wv = tid >> 6;
  const int l31 = lane & 31;
  const int hi = lane >> 5;
  const int koff = hi << 3;
  const int b = blockIdx.x / strips;
  const int strip = blockIdx.x - b * strips;
  const long base = (long)b * SEQ + (long)strip * (nch * 32);

  // W fragments in registers: this wave's 32-col tile of the q|k projection
  short8 wf[8];
  {
    const int col = (wv << 5) + l31;
    #pragma unroll
    for (int ks = 0; ks < 8; ++ks)
      #pragma unroll
      for (int j = 0; j < 8; ++j)
        wf[ks][j] = bf16b(Wqkv[(ks * 16 + koff + j) * 384 + col]);
  }

  const int lr = tid >> 4;
  const int lc = (tid & 15) << 3;

  {  // preload chunk 0
    const float* xp = x + (base + lr) * 128 + lc;
    f32x4 a0 = *(const f32x4*)xp;
    f32x4 a1 = *(const f32x4*)(xp + 4);
    short8 xv;
    #pragma unroll
    for (int j = 0; j < 4; ++j) { xv[j] = bf16b(a0[j]); xv[4 + j] = bf16b(a1[j]); }
    *(short8*)&xs[0][SWZ(lr, lc)] = xv;
  }
  __syncthreads();

  f32x16 ctx0 = {0.f};
  f32x16 ctx1 = {0.f};
  const int td = wv & 3;
  const int teb = (wv >> 2) << 1;
  const int h = wv >> 2;            // 0 = q half, 1 = k half
  const int tq = wv & 3;
  const float qs = h ? 1.0f : QSCALE;
  short* const dst = h ? kt : qt;
  const int cc = (tq << 5) + l31;   // channel within half

  int cur = 0;
  for (int ch = 0; ch < nch; ++ch) {
    // issue next chunk's loads early (land during proj+softmax)
    const int chn = (ch + 1 < nch) ? ch + 1 : ch;
    const float* xp = x + (base + chn * 32 + lr) * 128 + lc;
    f32x4 a0 = *(const f32x4*)xp;
    f32x4 a1 = *(const f32x4*)(xp + 4);

    // projection: this wave's 32x32 tile over K=128
    f32x16 acc = {0.f};
    #pragma unroll
    for (int ks = 0; ks < 8; ++ks)
      acc = mfma_pr(&xs[cur][SWZ(l31, ks * 16 + koff)], wf[ks], acc);

    // exp + per-tile row sums (no max-sub: logits ~N(0,1), exp safe in f32)
    float e[16];
    #pragma unroll
    for (int r = 0; r < 16; ++r) {
      e[r] = __expf(acc[r]);
      float s = e[r];
      s += __shfl_xor(s, 1); s += __shfl_xor(s, 2); s += __shfl_xor(s, 4);
      s += __shfl_xor(s, 8); s += __shfl_xor(s, 16);
      if (l31 == 0) sumbuf[h][(r & 3) + ((r >> 2) << 3) + (hi << 2)][tq] = s;
    }
    __syncthreads();                       // B1

    // combine across 4 tiles + write q^T/k^T (packed 4 rows = 8B per write)
    #pragma unroll
    for (int g = 0; g < 4; ++g) {
      s16x4 pk;
      #pragma unroll
      for (int q = 0; q < 4; ++q) {
        const int row = q + (g << 3) + (hi << 2);
        const f32x4 sv = *(const f32x4*)&sumbuf[h][row][0];
        const float inv = qs * __builtin_amdgcn_rcpf(sv[0] + sv[1] + sv[2] + sv[3]);
        pk[q] = bf16b(e[(g << 2) + q] * inv);
      }
      *(s16x4*)&dst[TSWZ(cc, (g << 3) + (hi << 2))] = pk;
    }
    __syncthreads();                       // B2

    {  // stage next chunk into the other buffer
      short8 xv;
      #pragma unroll
      for (int j = 0; j < 4; ++j) { xv[j] = bf16b(a0[j]); xv[4 + j] = bf16b(a1[j]); }
      *(short8*)&xs[cur ^ 1][SWZ(lr, lc)] = xv;
    }

    // ctx += q^T k : 2 ksteps x 2 tiles per wave
    #pragma unroll
    for (int ks = 0; ks < 2; ++ks) {
      const int kk = (ks << 4) + koff;
      const short* pa = &qt[TSWZ((td << 5) + l31, kk)];
      ctx0 = mfma_pp(pa, &kt[TSWZ((teb << 5) + l31, kk)], ctx0);
      ctx1 = mfma_pp(pa, &kt[TSWZ(((teb + 1) << 5) + l31, kk)], ctx1);
    }
    __syncthreads();                       // B3
    cur ^= 1;
  }

  float* pout = partials + (long)blockIdx.x * 16384;
  #pragma unroll
  for (int r = 0; r < 16; ++r) {
    const int drow = (td << 5) + (r & 3) + ((r >> 2) << 3) + (hi << 2);
    pout[(drow << 7) + (teb << 5) + l31] = ctx0[r];
    pout[(drow << 7) + ((teb + 1) << 5) + l31] = ctx1[r];
  }
}

// ---------------------------------------------------------------------------
// Reduce partials -> ctx[b]   (grid 128 = 8 batches x 16 slices)
// ---------------------------------------------------------------------------
__global__ void la_reduce(const float* __restrict__ partials, float* __restrict__ ctx,
                          int strips) {
  const int b = blockIdx.x >> 4;
  const int sl = blockIdx.x & 15;
  const int idx = (sl << 10) + ((int)threadIdx.x << 2);
  f32x4 acc = {0.f};
  for (int st = 0; st < strips; ++st)
    acc += *(const f32x4*)(partials + ((long)(b * strips + st) << 14) + idx);
  *(f32x4*)(ctx + ((long)b << 14) + idx) = acc;
}

// ---------------------------------------------------------------------------
// Mt[b][d'][e] = sum_d ctx[b][d][e] * Wout[d][d']   (bf16 out; grid 32)
// ---------------------------------------------------------------------------
__global__ void la_mkern(const float* __restrict__ ctx, const float* __restrict__ Wout,
                         short* __restrict__ Mtw) {
  __shared__ __align__(16) float cl[128 * 132];
  __shared__ float wo[128 * 32];
  const int tid = threadIdx.x;
  const int b = blockIdx.x >> 2;
  const int d0 = (blockIdx.x & 3) << 5;
  const float* cp = ctx + ((long)b << 14);
  for (int i = tid << 2; i < 16384; i += 1024) {
    f32x4 v = *(const f32x4*)(cp + i);
    *(f32x4*)&cl[(i >> 7) * 132 + (i & 127)] = v;
  }
  for (int i = tid; i < 128 * 32; i += 256) {
    wo[i] = Wout[((i >> 5) << 7) + d0 + (i & 31)];
  }
  __syncthreads();
  const int dq = tid >> 3;
  const int e0 = (tid & 7) << 4;
  float acc[16];
  #pragma unroll
  for (int i = 0; i < 16; ++i) acc[i] = 0.0f;
  for (int d = 0; d < 128; ++d) {
    const float w = wo[(d << 5) + dq];
    const float* c = &cl[d * 132 + e0];
    #pragma unroll
    for (int i = 0; i < 16; ++i) acc[i] += c[i] * w;
  }
  short* dstp = Mtw + ((long)b << 14) + ((long)(d0 + dq) << 7) + e0;
  #pragma unroll
  for (int i = 0; i < 16; ++i) dstp[i] = bf16b(acc[i]);
}

// ---------------------------------------------------------------------------
// Pass 2: v proj + softmax(in-reg) + out = v @ Mt^T + bias.  grid 512, 512 thr.
// ---------------------------------------------------------------------------
__global__ __launch_bounds__(512, 4)
void la_pass2(const float* __restrict__ x, const float* __restrict__ Wqkv,
              const float* __restrict__ bout, const short* __restrict__ Mtw,
              float* __restrict__ out) {
  __shared__ __align__(16) short xs[2][64 * 128];   // 32 KB dbuf
  __shared__ __align__(16) short vs[64 * 128];      // 16 KB
  __shared__ __align__(16) float sumbuf[64][4];     // 1 KB

  const int tid = threadIdx.x;
  const int lane = tid & 63;
  const int wv = tid >> 6;
  const int l31 = lane & 31;
  const int hi = lane >> 5;
  const int koff = hi << 3;
  const int rt = wv >> 2;
  const int ct = wv & 3;
  const int b = blockIdx.x >> 6;
  const int strip = blockIdx.x & 63;
  const long base = (long)b * SEQ + (long)strip * 512;

  short8 wvf[8];
  short8 mtf[8];
  {
    const int col = (ct << 5) + l31;
    #pragma unroll
    for (int ks = 0; ks < 8; ++ks) {
      #pragma unroll
      for (int j = 0; j < 8; ++j)
        wvf[ks][j] = bf16b(Wqkv[(ks * 16 + koff + j) * 384 + 256 + col]);
      mtf[ks] = *(const short8*)(Mtw + ((long)b << 14) + (col << 7) + (ks << 4) + koff);
    }
  }
  const float bias = bout[(ct << 5) + l31];

  const int lr = tid >> 3;
  const int lc = (tid & 7) << 4;

  {  // preload chunk 0
    const float* xp = x + (base + lr) * 128 + lc;
    f32x4 a0 = *(const f32x4*)xp;
    f32x4 a1 = *(const f32x4*)(xp + 4);
    f32x4 a2 = *(const f32x4*)(xp + 8);
    f32x4 a3 = *(const f32x4*)(xp + 12);
    short8 v0, v1;
    #pragma unroll
    for (int j = 0; j < 4; ++j) {
      v0[j] = bf16b(a0[j]); v0[4 + j] = bf16b(a1[j]);
      v1[j] = bf16b(a2[j]); v1[4 + j] = bf16b(a3[j]);
    }
    *(short8*)&xs[0][SWZ(lr, lc)] = v0;
    *(short8*)&xs[0][SWZ(lr, lc + 8)] = v1;
  }
  __syncthreads();

  int cur = 0;
  for (int ch = 0; ch < 8; ++ch) {
    const int chn = (ch + 1 < 8) ? ch + 1 : ch;
    const float* xp = x + (base + chn * 64 + lr) * 128 + lc;
    f32x4 a0 = *(const f32x4*)xp;
    f32x4 a1 = *(const f32x4*)(xp + 4);
    f32x4 a2 = *(const f32x4*)(xp + 8);
    f32x4 a3 = *(const f32x4*)(xp + 12);

    // v projection: wave (rt,ct) owns one 32x32 tile of [64 x 128]
    f32x16 acc = {0.f};
    #pragma unroll
    for (int ks = 0; ks < 8; ++ks)
      acc = mfma_pr(&xs[cur][SWZ((rt << 5) + l31, (ks << 4) + koff)], wvf[ks], acc);

    float e[16];
    #pragma unroll
    for (int r = 0; r < 16; ++r) {
      e[r] = __expf(acc[r]);
      float s = e[r];
      s += __shfl_xor(s, 1); s += __shfl_xor(s, 2); s += __shfl_xor(s, 4);
      s += __shfl_xor(s, 8); s += __shfl_xor(s, 16);
      if (l31 == 0) sumbuf[(rt << 5) + (r & 3) + ((r >> 2) << 3) + (hi << 2)][ct] = s;
    }
    __syncthreads();                     // B1

    const int ecol = (ct << 5) + l31;
    #pragma unroll
    for (int r = 0; r < 16; ++r) {
      const int row = (rt << 5) + (r & 3) + ((r >> 2) << 3) + (hi << 2);
      const f32x4 sv = *(const f32x4*)&sumbuf[row][0];
      const float inv = __builtin_amdgcn_rcpf(sv[0] + sv[1] + sv[2] + sv[3]);
      vs[SWZ(row, ecol)] = bf16b(e[r] * inv);
    }
    {  // stage next chunk
      short8 v0, v1;
      #pragma unroll
      for (int j = 0; j < 4; ++j) {
        v0[j] = bf16b(a0[j]); v0[4 + j] = bf16b(a1[j]);
        v1[j] = bf16b(a2[j]); v1[4 + j] = bf16b(a3[j]);
      }
      *(short8*)&xs[cur ^ 1][SWZ(lr, lc)] = v0;
      *(short8*)&xs[cur ^ 1][SWZ(lr, lc + 8)] = v1;
    }
    __syncthreads();                     // B2

    f32x16 oacc = {0.f};
    #pragma unroll
    for (int ks = 0; ks < 8; ++ks)
      oacc = mfma_pr(&vs[SWZ((rt << 5) + l31, (ks << 4) + koff)], mtf[ks], oacc);

    float* op = out + (base + ch * 64) * 128 + (ct << 5) + l31;
    #pragma unroll
    for (int r = 0; r < 16; ++r) {
      const int row = (rt << 5) + (r & 3) + ((r >> 2) << 3) + (hi << 2);
      op[(long)row << 7] = oacc[r] + bias;
    }
    __syncthreads();                     // B3
    cur ^= 1;
  }
}

extern "C" void kernel_launch(void* const* d_in, const int* in_sizes, int n_in,
                              void* d_out, int out_size, void* d_ws, size_t ws_size,
                              hipStream_t stream) {
  const float* x = (const float*)d_in[0];
  const float* Wqkv = (const float*)d_in[1];
  const float* Wout = (const float*)d_in[2];
  const float* bout = (const float*)d_in[3];
  float* out = (float*)d_out;

  const size_t need64 = (size_t)512 * 16384 * 4 + (size_t)8 * 16384 * 4 + (size_t)8 * 16384 * 2;
  const int strips = (ws_size >= need64) ? 64 : 32;
  const int nch = SEQ / (strips * 32);

  float* partials = (float*)d_ws;                        // 8*strips * 16384 f32
  float* ctx = partials + (size_t)8 * strips * 16384;    // 8 * 16384 f32
  short* Mtw = (short*)(ctx + 8 * 16384);                // 8 * 16384 bf16

  la_pass1<<<dim3(8 * strips), dim3(512), 0, stream>>>(x, Wqkv, partials, strips, nch);
  la_reduce<<<dim3(128), dim3(256), 0, stream>>>(partials, ctx, strips);
  la_mkern<<<dim3(32), dim3(256), 0, stream>>>(ctx, Wout, Mtw);
  la_pass2<<<dim3(512), dim3(512), 0, stream>>>(x, Wqkv, bout, Mtw, out);
}

// Round 3
// 205.796 us; speedup vs baseline: 1.2184x; 1.2184x over previous
//
#include <hip/hip_runtime.h>

#define SEQ 32768
#define QSCALE 0.08838834764831845f

typedef __attribute__((ext_vector_type(8))) short short8;
typedef __attribute__((ext_vector_type(8))) __bf16 bf16x8;
typedef __attribute__((ext_vector_type(16))) float f32x16;
typedef __attribute__((ext_vector_type(4))) float f32x4;
typedef __attribute__((ext_vector_type(4))) int int4v;

// [R][128]-short tile swizzle: XOR byte bits 4..6 with row&7 (conflict-tamed b128)
#define SWZ(r, c) ((((r) << 7) + (c)) ^ (((r) & 7) << 3))

__device__ __forceinline__ short bf16b(float f) {
  unsigned u = __builtin_bit_cast(unsigned, f);
  u += 0x7fffu + ((u >> 16) & 1u);  // RNE
  return (short)(u >> 16);
}

__device__ __forceinline__ int cvtpk(float lo, float hi) {
  int r;
  asm("v_cvt_pk_bf16_f32 %0, %1, %2" : "=v"(r) : "v"(lo), "v"(hi));
  return r;
}

__device__ __forceinline__ f32x16 mfma_ii(int4v a, int4v b, f32x16 c) {
  return __builtin_amdgcn_mfma_f32_32x32x16_bf16(
      __builtin_bit_cast(bf16x8, a), __builtin_bit_cast(bf16x8, b), c, 0, 0, 0);
}

// C-layout (16 f32: row n=(r&3)+8*(r>>2)+4*hi, lane=l&31) -> A/B-frag for one
// K=16 step: reg j must hold n = hi*8 + j. Needs only a hi-half exchange.
__device__ __forceinline__ int4v build_frag(float e0, float e1, float e2, float e3,
                                            float e4, float e5, float e6, float e7,
                                            int hi) {
  int t0 = cvtpk(e0, e1), t1 = cvtpk(e2, e3);
  int t2 = cvtpk(e4, e5), t3 = cvtpk(e6, e7);
  const int u0 = __shfl_xor(t2, 32), u1 = __shfl_xor(t3, 32);
  const int u2 = __shfl_xor(t0, 32), u3 = __shfl_xor(t1, 32);
  int4v f;
  f[0] = hi ? u0 : t0;   // n{0,1} | n{8,9}
  f[1] = hi ? u1 : t1;   // n{2,3} | n{10,11}
  f[2] = hi ? t2 : u2;   // n{4,5} | n{12,13}
  f[3] = hi ? t3 : u3;   // n{6,7} | n{14,15}
  return f;
}

// ---------------------------------------------------------------------------
// Pass 1: q,k proj (o1+o2) + softmax + ctx partial.  grid 8*strips, 512 thr.
// 2 barriers/chunk; sums via o2 (lane-local); frags via in-reg transpose.
// ---------------------------------------------------------------------------
__global__ __launch_bounds__(512, 4)
void la_pass1(const float* __restrict__ x, const float* __restrict__ Wqkv,
              float* __restrict__ partials, int strips, int nch) {
  __shared__ __align__(16) short xs[2][32 * 128];   // 16 KB dbuf
  __shared__ int4v fragbuf[16][64];                 // 16 KB (q:0-7, k:8-15)
  __shared__ float sumbuf[2][32][4];                // 1 KB

  const int tid = threadIdx.x;
  const int lane = tid & 63;
  const int wv = tid >> 6;
  const int l31 = lane & 31;
  const int hi = lane >> 5;
  const int koff = hi << 3;
  const int h = wv >> 2;            // 0=q wave, 1=k wave (proj tile half)
  const int c = wv & 3;             // proj col-tile
  const int td = wv & 3;            // ctx d-tile
  const int teb = h << 1;           // ctx first e-tile
  const int b = blockIdx.x / strips;
  const int strip = blockIdx.x - b * strips;
  const long base = (long)b * SEQ + (long)strip * (nch * 32);

  // W fragments (this wave's 32-col tile), packed bf16 pairs
  int4v wf[8];
  {
    const int col = (h << 7) + (c << 5) + l31;
    #pragma unroll
    for (int ks = 0; ks < 8; ++ks)
      #pragma unroll
      for (int a = 0; a < 4; ++a)
        wf[ks][a] = cvtpk(Wqkv[(ks * 16 + koff + 2 * a) * 384 + col],
                          Wqkv[(ks * 16 + koff + 2 * a + 1) * 384 + col]);
  }

  const int lr = tid >> 4;
  const int lc = (tid & 15) << 3;
  {  // preload chunk 0
    const float* xp = x + (base + lr) * 128 + lc;
    f32x4 a0 = *(const f32x4*)xp;
    f32x4 a1 = *(const f32x4*)(xp + 4);
    short8 xv;
    #pragma unroll
    for (int j = 0; j < 4; ++j) { xv[j] = bf16b(a0[j]); xv[4 + j] = bf16b(a1[j]); }
    *(short8*)&xs[0][SWZ(lr, lc)] = xv;
  }
  __syncthreads();

  f32x16 ctx0 = {0.f}, ctx1 = {0.f};
  int cur = 0;
  for (int ch = 0; ch < nch; ++ch) {
    const int chn = (ch + 1 < nch) ? ch + 1 : ch;
    const float* xp = x + (base + chn * 32 + lr) * 128 + lc;
    f32x4 a0 = *(const f32x4*)xp;
    f32x4 a1 = *(const f32x4*)(xp + 4);

    // projection both orientations from the same LDS fragment reads
    f32x16 po1 = {0.f}, po2 = {0.f};
    #pragma unroll
    for (int ks = 0; ks < 8; ++ks) {
      const int4v xf = *(const int4v*)&xs[cur][SWZ(l31, ks * 16 + koff)];
      po1 = mfma_ii(xf, wf[ks], po1);   // P[n in regs][ch in lanes]
      po2 = mfma_ii(wf[ks], xf, po2);   // P^T[ch in regs][n in lanes]
    }

    // o2 sums: lane-local over 16 channel-regs + cross-half
    float s = 0.f;
    #pragma unroll
    for (int r = 0; r < 16; ++r) s += __expf(po2[r]);
    s += __shfl_xor(s, 32);
    if (!hi) sumbuf[h][l31][c] = s;

    // o1 exp (values)
    float e1[16];
    #pragma unroll
    for (int r = 0; r < 16; ++r) e1[r] = __expf(po1[r]);

    {  // stage next chunk (vmcnt wait lands here, ~600cy after issue)
      short8 xv;
      #pragma unroll
      for (int j = 0; j < 4; ++j) { xv[j] = bf16b(a0[j]); xv[4 + j] = bf16b(a1[j]); }
      *(short8*)&xs[cur ^ 1][SWZ(lr, lc)] = xv;
    }
    __syncthreads();                    // B1: sumbuf + stage visible

    // fold all normalization into q: q' = e_q * QSCALE/(sq*sk); k stays raw
    if (h == 0) {
      #pragma unroll
      for (int r = 0; r < 16; ++r) {
        const int n = (r & 3) + ((r >> 2) << 3) + (hi << 2);
        const f32x4 sq = *(const f32x4*)&sumbuf[0][n][0];
        const f32x4 sk = *(const f32x4*)&sumbuf[1][n][0];
        const float fs = (sq[0] + sq[1] + sq[2] + sq[3]) *
                         (sk[0] + sk[1] + sk[2] + sk[3]);
        e1[r] *= QSCALE * __builtin_amdgcn_rcpf(fs);
      }
    }

    const int4v f0 = build_frag(e1[0], e1[1], e1[2], e1[3],
                                e1[4], e1[5], e1[6], e1[7], hi);
    const int4v f1 = build_frag(e1[8], e1[9], e1[10], e1[11],
                                e1[12], e1[13], e1[14], e1[15], hi);
    fragbuf[(h << 3) + (c << 1) + 0][lane] = f0;
    fragbuf[(h << 3) + (c << 1) + 1][lane] = f1;
    __syncthreads();                    // B2: frags ready

    #pragma unroll
    for (int ks = 0; ks < 2; ++ks) {
      const int4v aq = fragbuf[(td << 1) + ks][lane];
      const int4v bk0 = fragbuf[8 + (teb << 1) + ks][lane];
      const int4v bk1 = fragbuf[8 + ((teb + 1) << 1) + ks][lane];
      ctx0 = mfma_ii(aq, bk0, ctx0);
      ctx1 = mfma_ii(aq, bk1, ctx1);
    }
    cur ^= 1;
  }

  float* pout = partials + (long)blockIdx.x * 16384;
  #pragma unroll
  for (int r = 0; r < 16; ++r) {
    const int drow = (td << 5) + (r & 3) + ((r >> 2) << 3) + (hi << 2);
    pout[(drow << 7) + (teb << 5) + l31] = ctx0[r];
    pout[(drow << 7) + ((teb + 1) << 5) + l31] = ctx1[r];
  }
}

// ---------------------------------------------------------------------------
// Reduce partials -> ctx[b]   (grid 128 = 8 batches x 16 slices)
// ---------------------------------------------------------------------------
__global__ void la_reduce(const float* __restrict__ partials, float* __restrict__ ctx,
                          int strips) {
  const int b = blockIdx.x >> 4;
  const int sl = blockIdx.x & 15;
  const int idx = (sl << 10) + ((int)threadIdx.x << 2);
  f32x4 acc = {0.f};
  for (int st = 0; st < strips; ++st)
    acc += *(const f32x4*)(partials + ((long)(b * strips + st) << 14) + idx);
  *(f32x4*)(ctx + ((long)b << 14) + idx) = acc;
}

// ---------------------------------------------------------------------------
// Mt[b][d'][e] = sum_d ctx[b][d][e] * Wout[d][d']   (bf16 out; grid 32)
// ---------------------------------------------------------------------------
__global__ void la_mkern(const float* __restrict__ ctx, const float* __restrict__ Wout,
                         short* __restrict__ Mtw) {
  __shared__ __align__(16) float cl[128 * 132];
  __shared__ float wo[128 * 32];
  const int tid = threadIdx.x;
  const int b = blockIdx.x >> 2;
  const int d0 = (blockIdx.x & 3) << 5;
  const float* cp = ctx + ((long)b << 14);
  for (int i = tid << 2; i < 16384; i += 1024) {
    f32x4 v = *(const f32x4*)(cp + i);
    *(f32x4*)&cl[(i >> 7) * 132 + (i & 127)] = v;
  }
  for (int i = tid; i < 128 * 32; i += 256)
    wo[i] = Wout[((i >> 5) << 7) + d0 + (i & 31)];
  __syncthreads();
  const int dq = tid >> 3;
  const int e0 = (tid & 7) << 4;
  float acc[16];
  #pragma unroll
  for (int i = 0; i < 16; ++i) acc[i] = 0.0f;
  for (int d = 0; d < 128; ++d) {
    const float w = wo[(d << 5) + dq];
    const float* cr = &cl[d * 132 + e0];
    #pragma unroll
    for (int i = 0; i < 16; ++i) acc[i] += cr[i] * w;
  }
  short* dstp = Mtw + ((long)b << 14) + ((long)(d0 + dq) << 7) + e0;
  #pragma unroll
  for (int i = 0; i < 16; ++i) dstp[i] = bf16b(acc[i]);
}

// ---------------------------------------------------------------------------
// Pass 2: barrier-free. Each wave owns 64 rows: v-proj (o2) + softmax
// (lane-local) + out = v@Mt^T + bias. W_v and Mt staged once in LDS.
// grid 512 blocks x 512 thr (8 waves); 2 blocks/CU.
// ---------------------------------------------------------------------------
__global__ __launch_bounds__(512, 4)
void la_pass2(const float* __restrict__ x, const float* __restrict__ Wqkv,
              const float* __restrict__ bout, const short* __restrict__ Mtw,
              float* __restrict__ out) {
  __shared__ __align__(16) short WvL[128 * 128];   // W_v^T [ch][dim], 32 KB
  __shared__ __align__(16) short MtL[128 * 128];   // Mt [d'][e], 32 KB

  const int tid = threadIdx.x;
  const int lane = tid & 63;
  const int wv = tid >> 6;
  const int l31 = lane & 31;
  const int hi = lane >> 5;
  const int koff = hi << 3;
  const int b = blockIdx.x >> 6;

  for (int i = tid; i < 16384; i += 512) {
    const int dim = i >> 7, ch = i & 127;
    WvL[SWZ(ch, dim)] = bf16b(Wqkv[dim * 384 + 256 + ch]);
  }
  {
    const short* mp = Mtw + ((long)b << 14);
    for (int i = tid << 3; i < 16384; i += 4096)
      *(short8*)&MtL[SWZ(i >> 7, i & 127)] = *(const short8*)(mp + i);
  }
  float bias[4];
  #pragma unroll
  for (int dt = 0; dt < 4; ++dt) bias[dt] = bout[dt * 32 + l31];
  __syncthreads();   // only barrier in the kernel

  const long row0 = (long)blockIdx.x * 512 + wv * 64;
  #pragma unroll 1
  for (int nt = 0; nt < 2; ++nt) {
    const long n0 = row0 + nt * 32;
    const float* xp = x + (n0 + l31) * 128 + koff;

    // v-proj, o2 orientation: C[e in regs][n=l31]; 4 e-tiles
    f32x16 a0 = {0.f}, a1 = {0.f}, a2 = {0.f}, a3 = {0.f};
    #pragma unroll
    for (int ks = 0; ks < 8; ++ks) {
      const f32x4 u = *(const f32x4*)(xp + ks * 16);
      const f32x4 v = *(const f32x4*)(xp + ks * 16 + 4);
      int4v xf;
      xf[0] = cvtpk(u[0], u[1]); xf[1] = cvtpk(u[2], u[3]);
      xf[2] = cvtpk(v[0], v[1]); xf[3] = cvtpk(v[2], v[3]);
      a0 = mfma_ii(*(const int4v*)&WvL[SWZ(l31, ks * 16 + koff)], xf, a0);
      a1 = mfma_ii(*(const int4v*)&WvL[SWZ(32 + l31, ks * 16 + koff)], xf, a1);
      a2 = mfma_ii(*(const int4v*)&WvL[SWZ(64 + l31, ks * 16 + koff)], xf, a2);
      a3 = mfma_ii(*(const int4v*)&WvL[SWZ(96 + l31, ks * 16 + koff)], xf, a3);
    }

    // softmax: exp + fully lane-local sum (64 regs + cross-half)
    float s = 0.f;
    #pragma unroll
    for (int r = 0; r < 16; ++r) {
      a0[r] = __expf(a0[r]); s += a0[r];
      a1[r] = __expf(a1[r]); s += a1[r];
      a2[r] = __expf(a2[r]); s += a2[r];
      a3[r] = __expf(a3[r]); s += a3[r];
    }
    s += __shfl_xor(s, 32);
    const float inv = __builtin_amdgcn_rcpf(s);
    #pragma unroll
    for (int r = 0; r < 16; ++r) {
      a0[r] *= inv; a1[r] *= inv; a2[r] *= inv; a3[r] *= inv;
    }

    // A-fragments for out-GEMM (K=e): same in-reg transpose per e-tile
    int4v vf[8];
    vf[0] = build_frag(a0[0], a0[1], a0[2], a0[3], a0[4], a0[5], a0[6], a0[7], hi);
    vf[1] = build_frag(a0[8], a0[9], a0[10], a0[11], a0[12], a0[13], a0[14], a0[15], hi);
    vf[2] = build_frag(a1[0], a1[1], a1[2], a1[3], a1[4], a1[5], a1[6], a1[7], hi);
    vf[3] = build_frag(a1[8], a1[9], a1[10], a1[11], a1[12], a1[13], a1[14], a1[15], hi);
    vf[4] = build_frag(a2[0], a2[1], a2[2], a2[3], a2[4], a2[5], a2[6], a2[7], hi);
    vf[5] = build_frag(a2[8], a2[9], a2[10], a2[11], a2[12], a2[13], a2[14], a2[15], hi);
    vf[6] = build_frag(a3[0], a3[1], a3[2], a3[3], a3[4], a3[5], a3[6], a3[7], hi);
    vf[7] = build_frag(a3[8], a3[9], a3[10], a3[11], a3[12], a3[13], a3[14], a3[15], hi);

    // out[n][d'] = sum_e v[n][e] * Mt[d'][e]  (+bias), 4 d'-tiles
    #pragma unroll
    for (int dt = 0; dt < 4; ++dt) {
      f32x16 o = {0.f};
      #pragma unroll
      for (int k = 0; k < 8; ++k)
        o = mfma_ii(vf[k], *(const int4v*)&MtL[SWZ(dt * 32 + l31, k * 16 + koff)], o);
      float* op = out + n0 * 128 + dt * 32 + l31;
      #pragma unroll
      for (int r = 0; r < 16; ++r)
        op[((r & 3) + ((r >> 2) << 3) + (hi << 2)) * 128] = o[r] + bias[dt];
    }
  }
}

extern "C" void kernel_launch(void* const* d_in, const int* in_sizes, int n_in,
                              void* d_out, int out_size, void* d_ws, size_t ws_size,
                              hipStream_t stream) {
  const float* x = (const float*)d_in[0];
  const float* Wqkv = (const float*)d_in[1];
  const float* Wout = (const float*)d_in[2];
  const float* bout = (const float*)d_in[3];
  float* out = (float*)d_out;

  const size_t need64 = (size_t)512 * 16384 * 4 + (size_t)8 * 16384 * 4 + (size_t)8 * 16384 * 2;
  const int strips = (ws_size >= need64) ? 64 : 32;
  const int nch = SEQ / (strips * 32);

  float* partials = (float*)d_ws;                        // 8*strips * 16384 f32
  float* ctx = partials + (size_t)8 * strips * 16384;    // 8 * 16384 f32
  short* Mtw = (short*)(ctx + 8 * 16384);                // 8 * 16384 bf16

  la_pass1<<<dim3(8 * strips), dim3(512), 0, stream>>>(x, Wqkv, partials, strips, nch);
  la_reduce<<<dim3(128), dim3(256), 0, stream>>>(partials, ctx, strips);
  la_mkern<<<dim3(32), dim3(256), 0, stream>>>(ctx, Wout, Mtw);
  la_pass2<<<dim3(512), dim3(512), 0, stream>>>(x, Wqkv, bout, Mtw, out);
}